// Round 10
// baseline (38.770 us; speedup 1.0000x reference)
//
#include <hip/hip_runtime.h>
#include <hip/hip_bf16.h>

// Problem constants
#define B_ 4
#define S_ 4096
#define H_ 1024
#define D_ 64
#define BK 64
#define KSTEPS (H_ / BK)   // 16

typedef short bf16x8 __attribute__((ext_vector_type(8)));
typedef float f32x4 __attribute__((ext_vector_type(4)));

__device__ inline unsigned short f2bf(float f) {
    union { float f; unsigned u; } v; v.f = f;
    return (unsigned short)((v.u + 0x7fffu + ((v.u >> 16) & 1u)) >> 16);
}
__device__ inline float bf2f(unsigned short u) {
    union { unsigned u; float f; } v; v.u = (unsigned)u << 16;
    return v.f;
}
__device__ inline bf16x8 cvt8(const float4& a, const float4& b) {
    bf16x8 r;
    r[0] = (short)f2bf(a.x); r[1] = (short)f2bf(a.y);
    r[2] = (short)f2bf(a.z); r[3] = (short)f2bf(a.w);
    r[4] = (short)f2bf(b.x); r[5] = (short)f2bf(b.y);
    r[6] = (short)f2bf(b.z); r[7] = (short)f2bf(b.w);
    return r;
}

// async global->LDS, 16B per lane; LDS dest is wave-uniform base (HW adds lane*16)
__device__ inline void gl_lds16(const unsigned short* g, unsigned short* l) {
    __builtin_amdgcn_global_load_lds(
        (const __attribute__((address_space(1))) unsigned int*)g,
        (__attribute__((address_space(3))) unsigned int*)l,
        16, 0, 0);
}

// ---------- prep_w3: Wk,Wv,Wq [H][D] fp32 -> WTs PRE-SWIZZLED bf16 ----------
// WTs[((pj*16+ks)*64 + d)*64 + sf*8 + j] = W_pj[h][d],
//   h = ks*64 + s*8 + j,  sf = s ^ (d&7)   (same involution the LDS read uses)
__global__ void prep_w3(const float* __restrict__ Wk, const float* __restrict__ Wv,
                        const float* __restrict__ Wq, unsigned short* __restrict__ WTs) {
    int gid = blockIdx.x * 256 + threadIdx.x;  // pj*65536 + d*1024 + h
    int pj = gid >> 16;
    int d = (gid >> 10) & 63;
    int h = gid & 1023;
    const float* W = (pj == 0) ? Wk : (pj == 1) ? Wv : Wq;
    int ks = h >> 6, s = (h >> 3) & 7, j = h & 7;
    int sf = s ^ (d & 7);
    WTs[((pj * 16 + ks) * 64 + d) * 64 + sf * 8 + j] = f2bf(W[h * 64 + d]);
}

// ---------- kv_moment11: K,V,Q fused; weights via global_load_lds; dbuf ----------
// LDS: x bufs L[0..4095],[4096..8191]; W[pj][buf] at 8192+(pj*2+buf)*4096.
// Read path (slot swizzle sf = slot ^ (row&7)) is byte-identical to round-8/9 proven.
__global__ __launch_bounds__(768)
void kv_moment11(const float* __restrict__ x, const unsigned short* __restrict__ WTs,
                 unsigned short* __restrict__ pMb, unsigned short* __restrict__ Qb) {
    int blk = blockIdx.x;            // 0..255
    int b = blk >> 6;
    int c = blk & 63;
    int s0 = c * 64;
    int tid = threadIdx.x;
    int w = tid >> 6, lane = tid & 63;
    int r = lane & 15, kg = lane >> 4;
    int sv = w & 3, pj = w >> 2;     // s-subtile 0..3; 0=K 1=V 2=Q

    __shared__ __align__(16) unsigned short L[32768];  // 64 KB

    // x staging map (threads 0..511, round-8 proven)
    int strow = tid >> 3, sts = tid & 7;
    int sf_st = sts ^ (strow & 7);
    // weight gl_lds chunks: wave w stages chunks ci = w*2, w*2+1 (24 total = 3pj x 8)
    int ci0 = w * 2, ci1 = w * 2 + 1;
    int cpj0 = ci0 >> 3, cch0 = ci0 & 7;
    int cpj1 = ci1 >> 3, cch1 = ci1 & 7;

    const float* xbase = x + ((size_t)b * S_ + s0) * H_;

    float4 xr0, xr1;

#define LOADX(KS) do { if (tid < 512) {                                       \
        const float* src = xbase + (size_t)strow * H_ + (KS) * BK + sts * 8;  \
        xr0 = *(const float4*)(src);                                          \
        xr1 = *(const float4*)(src + 4); } } while (0)
#define WRITEX(BUF) do { if (tid < 512)                                       \
        *(bf16x8*)&L[(BUF) * 4096 + strow * 64 + sf_st * 8] = cvt8(xr0, xr1); \
    } while (0)
#define GLLDSW(BUF, KS) do {                                                  \
        gl_lds16(WTs + ((cpj0 * 16 + (KS)) * 4096) + cch0 * 512 + lane * 8,   \
                 &L[8192 + (cpj0 * 2 + (BUF)) * 4096 + cch0 * 512]);          \
        gl_lds16(WTs + ((cpj1 * 16 + (KS)) * 4096) + cch1 * 512 + lane * 8,   \
                 &L[8192 + (cpj1 * 2 + (BUF)) * 4096 + cch1 * 512]);          \
    } while (0)

    // prologue: buf0 <- W(0), x(0); regs <- x(1)
    GLLDSW(0, 0);
    LOADX(0);
    WRITEX(0);
    LOADX(1);
    __syncthreads();   // vmcnt(0) drain: buf0 weights landed, x(1) in regs

    f32x4 acc[4] = {};
    int arow_off = (sv * 16 + r) * 64;

    for (int ks = 0; ks < KSTEPS; ++ks) {
        int cur = ks & 1;
        if (ks < KSTEPS - 1) {
            GLLDSW(cur ^ 1, ks + 1);   // async DMA into the free buffer
            WRITEX(cur ^ 1);           // x for ks+1 from regs
        }
        if (ks < KSTEPS - 2) LOADX(ks + 2);
#pragma unroll
        for (int kc = 0; kc < 2; ++kc) {
            int slot = kc * 4 + kg;
            int sf = (slot ^ (r & 7)) * 8;
            bf16x8 af = *(const bf16x8*)&L[cur * 4096 + arow_off + sf];
#pragma unroll
            for (int nt = 0; nt < 4; ++nt) {
                bf16x8 bw = *(const bf16x8*)&L[8192 + (pj * 2 + cur) * 4096 + (nt * 16 + r) * 64 + sf];
                acc[nt] = __builtin_amdgcn_mfma_f32_16x16x32_bf16(af, bw, acc[nt], 0, 0, 0);
            }
        }
        __syncthreads();   // drains DMA + loads; next buffer ready
    }

    // K,V -> LDS (round-8 proven D-layout); Q -> global Qb
    if (pj < 2) {
#pragma unroll
        for (int nt = 0; nt < 4; ++nt)
#pragma unroll
            for (int i = 0; i < 4; ++i)
                L[pj * 4096 + (sv * 16 + kg * 4 + i) * 64 + nt * 16 + r] = f2bf(acc[nt][i]);
    }
    __syncthreads();
    if (pj == 2) {
        unsigned short* qrow = Qb + ((size_t)b * S_ + s0 + sv * 16) * 64;
#pragma unroll
        for (int nt = 0; nt < 4; ++nt)
#pragma unroll
            for (int i = 0; i < 4; ++i)
                qrow[(kg * 4 + i) * 64 + nt * 16 + r] = f2bf(acc[nt][i]);
    } else if (w < 8) {
        // Stage 2 (round-8 proven): Mpart[e][d] = sum_{s<64} K[s][e]*V[s][d]
        int et = w & 3, dh2 = w >> 2;
        f32x4 accM[2] = {};
#pragma unroll
        for (int ks2 = 0; ks2 < 2; ++ks2) {
            bf16x8 afm;
#pragma unroll
            for (int i = 0; i < 8; ++i)
                afm[i] = (short)L[(ks2 * 32 + kg * 8 + i) * 64 + et * 16 + r];
#pragma unroll
            for (int t = 0; t < 2; ++t) {
                int nt = dh2 * 2 + t;
                bf16x8 bfv;
#pragma unroll
                for (int i = 0; i < 8; ++i)
                    bfv[i] = (short)L[4096 + (ks2 * 32 + kg * 8 + i) * 64 + nt * 16 + r];
                accM[t] = __builtin_amdgcn_mfma_f32_16x16x32_bf16(afm, bfv, accM[t], 0, 0, 0);
            }
        }
        // pMb layout [b][idx][chunk] (round-8 proven)
#pragma unroll
        for (int t = 0; t < 2; ++t)
#pragma unroll
            for (int i = 0; i < 4; ++i) {
                int idx = (et * 16 + kg * 4 + i) * 64 + (dh2 * 2 + t) * 16 + r;
                pMb[((size_t)b * 4096 + idx) * 64 + c] = f2bf(accM[t][i]);
            }
    }
#undef LOADX
#undef WRITEX
#undef GLLDSW
}

// ---------- PROVEN: reduce_m8 (contiguous 64-chunk read, folds 1/8) ----------
__global__ void reduce_m8(const unsigned short* __restrict__ pMb, float* __restrict__ M8) {
    int gid = blockIdx.x * 256 + threadIdx.x;  // 0..16383 = b*4096 + idx
    const unsigned short* p = pMb + (size_t)gid * 64;
    float s = 0.f;
#pragma unroll
    for (int j = 0; j < 8; ++j) {
        bf16x8 v = *(const bf16x8*)(p + j * 8);
#pragma unroll
        for (int e = 0; e < 8; ++e) s += bf2f((unsigned short)v[e]);
    }
    M8[gid] = s * 0.125f;
}

// ---------- PROVEN: final_qm ----------
__global__ __launch_bounds__(256)
void final_qm(const unsigned short* __restrict__ Qb, const float* __restrict__ M8,
              float* __restrict__ out) {
    int blk = blockIdx.x;            // 0..255
    int b = blk >> 6;
    int s0 = (blk & 63) * 64;
    int tid = threadIdx.x;
    int wv = tid >> 6, lane = tid & 63;
    int r = lane & 15, kg = lane >> 4;

    __shared__ unsigned short Ml[4096];  // M8 as bf16 [e][d]
#pragma unroll
    for (int j = 0; j < 16; ++j) {
        int i2 = j * 256 + tid;
        Ml[i2] = f2bf(M8[b * 4096 + i2]);
    }
    __syncthreads();

    const unsigned short* qrow = Qb + ((size_t)b * S_ + s0 + wv * 16 + r) * 64;
    f32x4 acc[4] = {};
#pragma unroll
    for (int ks2 = 0; ks2 < 2; ++ks2) {
        bf16x8 af = *(const bf16x8*)(qrow + ks2 * 32 + kg * 8);
#pragma unroll
        for (int nt = 0; nt < 4; ++nt) {
            bf16x8 bfm;
#pragma unroll
            for (int i = 0; i < 8; ++i)
                bfm[i] = (short)Ml[(ks2 * 32 + kg * 8 + i) * 64 + nt * 16 + r];
            acc[nt] = __builtin_amdgcn_mfma_f32_16x16x32_bf16(af, bfm, acc[nt], 0, 0, 0);
        }
    }
    float* orow = out + ((size_t)b * S_ + s0 + wv * 16) * 64;
#pragma unroll
    for (int nt = 0; nt < 4; ++nt)
#pragma unroll
        for (int i = 0; i < 4; ++i)
            orow[(kg * 4 + i) * 64 + nt * 16 + r] = acc[nt][i];
}

extern "C" void kernel_launch(void* const* d_in, const int* in_sizes, int n_in,
                              void* d_out, int out_size, void* d_ws, size_t ws_size,
                              hipStream_t stream) {
    const float* x  = (const float*)d_in[0];
    const float* Wk = (const float*)d_in[1];
    const float* Wq = (const float*)d_in[2];
    const float* Wv = (const float*)d_in[3];
    float* out = (float*)d_out;

    if (ws_size < 4653056) return;  // diagnostic guard

    char* ws = (char*)d_ws;
    // layout (total 4,653,056 B):
    // WTs[384K bf16 x3, pre-swizzled] | M8[64K fp32] | Qb[2M bf16] | pMb[2M bf16]
    unsigned short* WTs = (unsigned short*)(ws);
    float* M8           = (float*)(ws + 393216);
    unsigned short* Qb  = (unsigned short*)(ws + 458752);
    unsigned short* pMb = (unsigned short*)(ws + 2555904);

    prep_w3<<<768, 256, 0, stream>>>(Wk, Wv, Wq, WTs);
    kv_moment11<<<256, 768, 0, stream>>>(x, WTs, pMb, Qb);
    reduce_m8<<<64, 256, 0, stream>>>(pMb, M8);
    final_qm<<<256, 256, 0, stream>>>(Qb, M8, out);
}